// Round 7
// baseline (905.342 us; speedup 1.0000x reference)
//
#include <hip/hip_runtime.h>

typedef unsigned short u16;
typedef unsigned int u32;
typedef __attribute__((ext_vector_type(8))) short short8;
typedef __attribute__((ext_vector_type(4))) float floatx4;
typedef __attribute__((ext_vector_type(4))) float float4v;

#define B_ 32
#define T_ 168
#define NH_ 32
#define NM_ 64
#define E_ 384
#define HL_ 128
#define FUT_ 24
#define SLOPE_ 0.01f
#define XP_ 80     // x-window stride per batch (u16)
#define HP_ 144    // hbuf stride per batch (u16)
#define TW_ 84     // x-window depth (168 = 2*84)
#define WIH_LP 72  // Wih staging row stride (u16): 256 rows * 72 = 18432
#define WHH_LP 136 // Whh staging row stride (u16): 128 rows * 136 = 17408
#define WBUF_E 18432
#define CH1_ (-1.4426950408889634f)  // folded into i,f,o gate rows
#define CH2_ (2.8853900817779268f)   // folded into g gate rows

static __device__ __forceinline__ float b2f(u16 u) {
  u32 v = ((u32)u) << 16;
  return __builtin_bit_cast(float, v);
}
static __device__ __forceinline__ u16 f2bf(float f) {
  u32 x = __builtin_bit_cast(u32, f);
  u32 r = (x + 0x7fffu + ((x >> 16) & 1u)) >> 16;
  return (u16)r;
}
static __device__ __forceinline__ float fexp2(float x) { return __builtin_amdgcn_exp2f(x); }
static __device__ __forceinline__ float frcp(float x) { return __builtin_amdgcn_rcpf(x); }
// gates arrive PRE-SCALED by CH1_/CH2_ (folded into weights+bias at staging)
static __device__ __forceinline__ float sigm_pre(float x) { return frcp(1.0f + fexp2(x)); }
static __device__ __forceinline__ float tanh_pre(float x) { return 1.0f - 2.0f * frcp(1.0f + fexp2(x)); }
static __device__ __forceinline__ float tanh_fast(float x) {
  return 1.0f - 2.0f * frcp(1.0f + fexp2(2.8853900817779268f * x));
}
static __device__ __forceinline__ float sel4(floatx4 v, int r) {
  float m0 = (r & 1) ? v[1] : v[0];
  float m1 = (r & 1) ? v[3] : v[2];
  return (r & 2) ? m1 : m0;
}
static __device__ __forceinline__ float lrelu(float x) { return fmaxf(x, SLOPE_ * x); }

// Fused GNN + per-station LSTM + head.
// Grid: 512 WGs = 32 stations x 16 bg-pairs x 2 batches. 512 thr = 8 waves.
// LDS ~68 KB and launch_bounds(512,4) -> 2 independent WGs co-resident per CU:
// their barriers anti-phase, so each WG's stall window is filled by the other.
__launch_bounds__(512, 4)
__global__ void fused_kernel(const float* __restrict__ dm, const float* __restrict__ dh,
                             const int* __restrict__ eidx,
                             const float* __restrict__ Wroot, const float* __restrict__ Wrel,
                             const float* __restrict__ bgnn,
                             const float* __restrict__ Wih, const float* __restrict__ Whh,
                             const float* __restrict__ bih, const float* __restrict__ bhh,
                             const float* __restrict__ Wlin, const float* __restrict__ blin,
                             float* __restrict__ out) {
  const int s = blockIdx.x & 31;
  const int bg2 = blockIdx.x >> 5;  // 0..15, batches bg2*2 + {0,1}
  const int tid = threadIdx.x;
  const int w = tid >> 6;
  const int lane = tid & 63;
  const int cm = lane & 15;
  const int q = lane >> 4;
  const int b = cm & 1;    // real batch column (cols repeat with period 2)
  const int rho = cm >> 1; // duplicate-group role; roles 0..3 (cm<8) activate r=rho

  __shared__ __align__(16) u16 wbuf[WBUF_E];        // 36 KB weight staging
  __shared__ __align__(16) u16 xwin[TW_ * 2 * XP_]; // 26.25 KB rolling x-features
  __shared__ __align__(16) u16 hbuf[2 * 2 * HP_];   // [p][b][HP_]
  __shared__ float xh_lds[2][T_];
  __shared__ float ag_lds[2][T_];
  __shared__ float wr_s[64], wv_s[64], bg_s[64];
  __shared__ int srcs[E_];
  __shared__ int nsrc, iflag;

  // ---- A: init
  if (tid == 0) { nsrc = 0; iflag = 0; }
  for (int i = tid; i < 2 * 2 * HP_; i += 512) hbuf[i] = 0;
  __syncthreads();

  // ---- B: int64-vs-int32 edge_index probe
  {
    int odd = 0;
    for (int e = tid; e < E_; e += 512) odd |= eidx[2 * e + 1];
    if (odd) atomicOr(&iflag, 1);
  }
  __syncthreads();
  const bool i32 = iflag != 0;

  // ---- C: in-edges; small tensors; bias (gate-scale folded)
  for (int e = tid; e < E_; e += 512) {
    int se = i32 ? eidx[e] : eidx[2 * e];
    int de = i32 ? eidx[E_ + e] : eidx[2 * E_ + 2 * e];
    if (de == s) { int i = atomicAdd(&nsrc, 1); srcs[i] = se; }
  }
  if (tid < 64) { wr_s[tid] = Wroot[tid]; wv_s[tid] = Wrel[tid]; bg_s[tid] = bgnn[tid]; }
  for (int i = tid; i < 2 * T_; i += 512) {
    int bb = i / T_, t = i % T_;
    xh_lds[bb][t] = dh[((size_t)(bg2 * 2 + bb) * T_ + t) * NH_ + s];
  }
  floatx4 bias_init[4];
#pragma unroll
  for (int blk = 0; blk < 4; blk++) {
    const float sc = (blk == 2) ? CH2_ : CH1_;
#pragma unroll
    for (int r = 0; r < 4; r++) {
      const int nb = blk * 128 + w * 16 + q * 4 + r;
      bias_init[blk][r] = (bih[s * 512 + nb] + bhh[s * 512 + nb]) * sc;
    }
  }
  __syncthreads();

  // ---- D: per-(b,t) aggregation (avg ~4 in-edges/station)
  const int ns = nsrc;
  for (int i = tid; i < 2 * T_; i += 512) {
    int bb = i / T_, t = i % T_;
    size_t gb = (size_t)(bg2 * 2 + bb) * T_ + t;
    float a = 0.f;
    for (int j = 0; j < ns; j++) {
      int sr = srcs[j];
      a += (sr < NH_) ? dh[gb * NH_ + sr] : dm[gb * NM_ + (sr - NH_)];
    }
    ag_lds[bb][t] = a;
  }

  // ---- W: staged weight load, 6 fully-unrolled rounds, static Af indices.
  short8 Af[4][6];
  const int nl = w * 16 + cm;  // gate-row within a 128-block (A row m = cm)
  // W1a: Wih rows 0..255 -> Af blk 0,1 (scale CH1)
  __syncthreads();
  {
    const float* g = Wih + (size_t)s * 512 * 64;
#pragma unroll
    for (int it = 0; it < 8; it++) {
      int j = tid + it * 512;  // 4096 float4s total for 256 rows
      float4v v = *(const float4v*)(g + 4 * j);
      u16* dst = wbuf + (j >> 4) * WIH_LP + (j & 15) * 4;
      dst[0] = f2bf(v[0] * CH1_); dst[1] = f2bf(v[1] * CH1_);
      dst[2] = f2bf(v[2] * CH1_); dst[3] = f2bf(v[3] * CH1_);
    }
  }
  __syncthreads();
#pragma unroll
  for (int blk = 0; blk < 2; blk++)
#pragma unroll
    for (int kk = 0; kk < 2; kk++)
      Af[blk][kk] = *(const short8*)(wbuf + (blk * 128 + nl) * WIH_LP + kk * 32 + q * 8);
  __syncthreads();
  // W1b: Wih rows 256..511 -> Af blk 2 (CH2), blk 3 (CH1)
  {
    const float* g = Wih + ((size_t)s * 512 + 256) * 64;
#pragma unroll
    for (int it = 0; it < 8; it++) {
      int j = tid + it * 512;
      float4v v = *(const float4v*)(g + 4 * j);
      const float sc = ((j >> 4) < 128) ? CH2_ : CH1_;
      u16* dst = wbuf + (j >> 4) * WIH_LP + (j & 15) * 4;
      dst[0] = f2bf(v[0] * sc); dst[1] = f2bf(v[1] * sc);
      dst[2] = f2bf(v[2] * sc); dst[3] = f2bf(v[3] * sc);
    }
  }
  __syncthreads();
#pragma unroll
  for (int blk = 2; blk < 4; blk++)
#pragma unroll
    for (int kk = 0; kk < 2; kk++)
      Af[blk][kk] = *(const short8*)(wbuf + ((blk - 2) * 128 + nl) * WIH_LP + kk * 32 + q * 8);
  // W2: Whh in 4 quarters of 128 rows; quarter qtr == gate block qtr
#pragma unroll
  for (int qtr = 0; qtr < 4; qtr++) {
    __syncthreads();
    const float* g = Whh + ((size_t)s * 512 + qtr * 128) * 128;
    const float sc = (qtr == 2) ? CH2_ : CH1_;
#pragma unroll
    for (int it = 0; it < 8; it++) {
      int j = tid + it * 512;  // 4096 float4s for 128 rows x 128
      float4v v = *(const float4v*)(g + 4 * j);
      u16* dst = wbuf + (j >> 5) * WHH_LP + (j & 31) * 4;
      dst[0] = f2bf(v[0] * sc); dst[1] = f2bf(v[1] * sc);
      dst[2] = f2bf(v[2] * sc); dst[3] = f2bf(v[3] * sc);
    }
    __syncthreads();
    if (qtr == 0) {
#pragma unroll
      for (int kk = 0; kk < 4; kk++)
        Af[0][2 + kk] = *(const short8*)(wbuf + nl * WHH_LP + kk * 32 + q * 8);
    } else if (qtr == 1) {
#pragma unroll
      for (int kk = 0; kk < 4; kk++)
        Af[1][2 + kk] = *(const short8*)(wbuf + nl * WHH_LP + kk * 32 + q * 8);
    } else if (qtr == 2) {
#pragma unroll
      for (int kk = 0; kk < 4; kk++)
        Af[2][2 + kk] = *(const short8*)(wbuf + nl * WHH_LP + kk * 32 + q * 8);
    } else {
#pragma unroll
      for (int kk = 0; kk < 4; kk++)
        Af[3][2 + kk] = *(const short8*)(wbuf + nl * WHH_LP + kk * 32 + q * 8);
    }
  }

  // ---- recurrent: 2 chunks x 84 steps; 1 barrier/step
  float c = 0.f;
  floatx4 accN[4];
#pragma unroll 1
  for (int ch = 0; ch < 2; ch++) {
    const int t0 = ch * TW_;
    __syncthreads();  // xwin free
    {  // refill x-window: x[i][bb][k] = lrelu(xh*wr + ag*wv + bg), pre 84 steps
      const int k = tid & 63;
      const int bb = (tid >> 6) & 1;
      const int th = tid >> 7;  // 0..3 quarters of TW_
      const float wrk = wr_s[k], wvk = wv_s[k], bgk = bg_s[k];
      u16* xw = xwin + bb * XP_ + k;
#pragma unroll 3
      for (int i = 0; i < TW_ / 4; i++) {
        const int t = th * (TW_ / 4) + i;
        const float xv = xh_lds[bb][t0 + t] * wrk + ag_lds[bb][t0 + t] * wvk + bgk;
        xw[t * (2 * XP_)] = f2bf(lrelu(xv));
      }
    }
    __syncthreads();
    // chunk-head accN(t0)
    {
      short8 Bx0 = *(const short8*)(xwin + b * XP_ + q * 8);
      short8 Bx1 = *(const short8*)(xwin + b * XP_ + 32 + q * 8);
#pragma unroll
      for (int blk = 0; blk < 4; blk++) {
        accN[blk] = __builtin_amdgcn_mfma_f32_16x16x32_bf16(Af[blk][0], Bx0, bias_init[blk], 0, 0, 0);
        accN[blk] = __builtin_amdgcn_mfma_f32_16x16x32_bf16(Af[blk][1], Bx1, accN[blk], 0, 0, 0);
      }
    }
#pragma unroll 2
    for (int i = 0; i < TW_; i++) {
      const int p = i & 1, pn = p ^ 1;
      short8 Bh[4];
#pragma unroll
      for (int kk = 0; kk < 4; kk++)
        Bh[kk] = *(const short8*)(hbuf + (p * 2 + b) * HP_ + kk * 32 + q * 8);

      floatx4 acc[4];
#pragma unroll
      for (int blk = 0; blk < 4; blk++)
        acc[blk] = __builtin_amdgcn_mfma_f32_16x16x32_bf16(Af[blk][2], Bh[0], accN[blk], 0, 0, 0);
#pragma unroll
      for (int kk = 1; kk < 4; kk++)
#pragma unroll
        for (int blk = 0; blk < 4; blk++)
          acc[blk] = __builtin_amdgcn_mfma_f32_16x16x32_bf16(Af[blk][2 + kk], Bh[kk], acc[blk], 0, 0, 0);

      // prefetch accN for step i+1 (no barrier dependence)
      if (i + 1 < TW_) {
        short8 Bx0 = *(const short8*)(xwin + (i + 1) * (2 * XP_) + b * XP_ + q * 8);
        short8 Bx1 = *(const short8*)(xwin + (i + 1) * (2 * XP_) + b * XP_ + 32 + q * 8);
#pragma unroll
        for (int blk = 0; blk < 4; blk++) {
          accN[blk] = __builtin_amdgcn_mfma_f32_16x16x32_bf16(Af[blk][0], Bx0, bias_init[blk], 0, 0, 0);
          accN[blk] = __builtin_amdgcn_mfma_f32_16x16x32_bf16(Af[blk][1], Bx1, accN[blk], 0, 0, 0);
        }
      }

      // activation: lanes cm<8 own element (row = w*16+q*4+rho, batch = b)
      if (cm < 8) {
        const float gi = sel4(acc[0], rho);
        const float gf = sel4(acc[1], rho);
        const float gg = sel4(acc[2], rho);
        const float go = sel4(acc[3], rho);
        c = sigm_pre(gf) * c + sigm_pre(gi) * tanh_pre(gg);
        const float hh = sigm_pre(go) * tanh_fast(c);
        hbuf[(pn * 2 + b) * HP_ + w * 16 + q * 4 + rho] = f2bf(hh);
      }
      __syncthreads();
    }
  }

  // ---- head: final h in hbuf p=0
  if (tid < 2 * FUT_) {
    const int bb = tid / FUT_;
    const int f = tid % FUT_;
    float a = blin[f];
#pragma unroll 8
    for (int k = 0; k < HL_; k++) a += b2f(hbuf[bb * HP_ + k]) * Wlin[f * HL_ + k];
    out[((size_t)(bg2 * 2 + bb) * NH_ + s) * FUT_ + f] = lrelu(a);
  }
}

extern "C" void kernel_launch(void* const* d_in, const int* in_sizes, int n_in,
                              void* d_out, int out_size, void* d_ws, size_t ws_size,
                              hipStream_t stream) {
  const float* dm = (const float*)d_in[0];
  const float* dh = (const float*)d_in[1];
  const int* eidx = (const int*)d_in[2];
  const float* Wroot = (const float*)d_in[3];
  const float* Wrel = (const float*)d_in[4];
  const float* bgnn = (const float*)d_in[5];
  const float* Wih = (const float*)d_in[6];
  const float* Whh = (const float*)d_in[7];
  const float* bih = (const float*)d_in[8];
  const float* bhh = (const float*)d_in[9];
  const float* Wlin = (const float*)d_in[10];
  const float* blin = (const float*)d_in[11];
  float* out = (float*)d_out;

  fused_kernel<<<512, 512, 0, stream>>>(dm, dh, eidx, Wroot, Wrel, bgnn, Wih, Whh,
                                        bih, bhh, Wlin, blin, out);
}

// Round 8
// 262.442 us; speedup vs baseline: 3.4497x; 3.4497x over previous
//
#include <hip/hip_runtime.h>

typedef unsigned short u16;
typedef unsigned int u32;
typedef __attribute__((ext_vector_type(8))) short short8;
typedef __attribute__((ext_vector_type(4))) float floatx4;
typedef __attribute__((ext_vector_type(4))) float float4v;

#define B_ 32
#define T_ 168
#define NH_ 32
#define NM_ 64
#define E_ 384
#define HL_ 128
#define FUT_ 24
#define SLOPE_ 0.01f
#define XP_ 80     // xbuf stride per batch (u16)
#define HP_ 144    // hbuf stride per (stream,p,b) row (u16)
#define WIH_LP 72  // Wih staging row stride (u16): 512*72 = 36864 fits xbuf overlay
#define WHH_LP 136 // Whh staging row stride (u16): 256*136 = 34816 fits xbuf overlay
#define CH1_ (-1.4426950408889634f)  // folded into i,f,o gate rows
#define CH2_ (2.8853900817779268f)   // folded into g gate rows

static __device__ __forceinline__ float b2f(u16 u) {
  u32 v = ((u32)u) << 16;
  return __builtin_bit_cast(float, v);
}
static __device__ __forceinline__ u16 f2bf(float f) {
  u32 x = __builtin_bit_cast(u32, f);
  u32 r = (x + 0x7fffu + ((x >> 16) & 1u)) >> 16;
  return (u16)r;
}
static __device__ __forceinline__ float fexp2(float x) { return __builtin_amdgcn_exp2f(x); }
static __device__ __forceinline__ float frcp(float x) { return __builtin_amdgcn_rcpf(x); }
// gates arrive PRE-SCALED by CH1_/CH2_ (folded into weights+bias at staging)
static __device__ __forceinline__ float sigm_pre(float x) { return frcp(1.0f + fexp2(x)); }
static __device__ __forceinline__ float tanh_pre(float x) { return 1.0f - 2.0f * frcp(1.0f + fexp2(x)); }
static __device__ __forceinline__ float tanh_fast(float x) {
  return 1.0f - 2.0f * frcp(1.0f + fexp2(2.8853900817779268f * x));
}
static __device__ __forceinline__ float sel4(floatx4 v, int r) {
  float m0 = (r & 1) ? v[1] : v[0];
  float m1 = (r & 1) ? v[3] : v[2];
  return (r & 2) ? m1 : m0;
}
static __device__ __forceinline__ float lrelu(float x) { return fmaxf(x, SLOPE_ * x); }

// Fused GNN + per-station LSTM + head. One WG/CU (2 waves/SIMD — register-
// resident weights need ~96 VGPR/lane, so >2 waves/SIMD is impossible).
// Dual independent batch-streams inside the WG: A = cols 0..7, B = cols 8..15;
// B's x-MFMAs + both Bh loads fill A's post-barrier latency. One barrier/step.
// Grid: 256 WGs = 32 stations x 8 bgroups x 4 batches (A:{0,1}, B:{2,3}).
__launch_bounds__(512, 2)
__global__ void fused_kernel(const float* __restrict__ dm, const float* __restrict__ dh,
                             const int* __restrict__ eidx,
                             const float* __restrict__ Wroot, const float* __restrict__ Wrel,
                             const float* __restrict__ bgnn,
                             const float* __restrict__ Wih, const float* __restrict__ Whh,
                             const float* __restrict__ bih, const float* __restrict__ bhh,
                             const float* __restrict__ Wlin, const float* __restrict__ blin,
                             float* __restrict__ out) {
  const int s = blockIdx.x & 31;
  const int bg = blockIdx.x >> 5;  // 0..7
  const int tid = threadIdx.x;
  const int w = tid >> 6;
  const int lane = tid & 63;
  const int cm = lane & 15;
  const int q = lane >> 4;
  const int b = cm & 1;          // batch within stream
  const int rho = (cm >> 1) & 3; // acc element this lane activates
  const int str = cm >> 3;       // stream 0 (A) / 1 (B)

  // xbuf: weight-staging overlay first, then full-T GNN features
  __shared__ __align__(16) u16 xbuf[T_ * 4 * XP_];     // 107.5 KB
  __shared__ __align__(16) u16 hbuf[2 * 2 * 2 * HP_];  // [str][p][b][HP_]
  __shared__ float xh_lds[4][T_];
  __shared__ float ag_lds[4][T_];
  __shared__ float wr_s[64], wv_s[64], bg_s[64];
  __shared__ int srcs[E_];
  __shared__ int nsrc, iflag;

  // ---- A: init
  if (tid == 0) { nsrc = 0; iflag = 0; }
  for (int i = tid; i < 2 * 2 * 2 * HP_; i += 512) hbuf[i] = 0;
  __syncthreads();

  // ---- B: int64-vs-int32 edge_index probe
  {
    int odd = 0;
    for (int e = tid; e < E_; e += 512) odd |= eidx[2 * e + 1];
    if (odd) atomicOr(&iflag, 1);
  }
  __syncthreads();
  const bool i32 = iflag != 0;

  // ---- C: in-edges; small tensors; bias (gate-scale folded)
  for (int e = tid; e < E_; e += 512) {
    int se = i32 ? eidx[e] : eidx[2 * e];
    int de = i32 ? eidx[E_ + e] : eidx[2 * E_ + 2 * e];
    if (de == s) { int i = atomicAdd(&nsrc, 1); srcs[i] = se; }
  }
  if (tid < 64) { wr_s[tid] = Wroot[tid]; wv_s[tid] = Wrel[tid]; bg_s[tid] = bgnn[tid]; }
  for (int i = tid; i < 4 * T_; i += 512) {
    int bb = i / T_, t = i % T_;
    xh_lds[bb][t] = dh[((size_t)(bg * 4 + bb) * T_ + t) * NH_ + s];
  }
  floatx4 bias_init[4];
#pragma unroll
  for (int blk = 0; blk < 4; blk++) {
    const float sc = (blk == 2) ? CH2_ : CH1_;
#pragma unroll
    for (int r = 0; r < 4; r++) {
      const int nb = blk * 128 + w * 16 + q * 4 + r;
      bias_init[blk][r] = (bih[s * 512 + nb] + bhh[s * 512 + nb]) * sc;
    }
  }
  __syncthreads();

  // ---- D: per-(b,t) aggregation (avg ~4 in-edges/station)
  const int ns = nsrc;
  for (int i = tid; i < 4 * T_; i += 512) {
    int bb = i / T_, t = i % T_;
    size_t gb = (size_t)(bg * 4 + bb) * T_ + t;
    float a = 0.f;
    for (int j = 0; j < ns; j++) {
      int sr = srcs[j];
      a += (sr < NH_) ? dh[gb * NH_ + sr] : dm[gb * NM_ + (sr - NH_)];
    }
    ag_lds[bb][t] = a;
  }

  // ---- W: coalesced LDS-staged weight load, 3 fully-unrolled rounds,
  // static Af indices (register residency), gate scales folded at convert.
  short8 Af[4][6];
  const int nl = w * 16 + cm;  // gate-row within a 128-block (A row m = cm)
  __syncthreads();
  {  // Round 1: all of Wih (512 rows x 64)
    const float* g = Wih + (size_t)s * 512 * 64;
#pragma unroll
    for (int it = 0; it < 16; it++) {
      int j = tid + it * 512;
      float4v v = *(const float4v*)(g + 4 * j);
      const float sc = (((j >> 4) >> 7) == 2) ? CH2_ : CH1_;
      u16* dst = xbuf + (j >> 4) * WIH_LP + (j & 15) * 4;
      dst[0] = f2bf(v[0] * sc); dst[1] = f2bf(v[1] * sc);
      dst[2] = f2bf(v[2] * sc); dst[3] = f2bf(v[3] * sc);
    }
  }
  __syncthreads();
#pragma unroll
  for (int blk = 0; blk < 4; blk++)
#pragma unroll
    for (int kk = 0; kk < 2; kk++)
      Af[blk][kk] = *(const short8*)(xbuf + (blk * 128 + nl) * WIH_LP + kk * 32 + q * 8);
  __syncthreads();
  {  // Round 2: Whh rows 0..255 (gate blocks 0,1 -> CH1)
    const float* g = Whh + (size_t)s * 512 * 128;
#pragma unroll
    for (int it = 0; it < 16; it++) {
      int j = tid + it * 512;
      float4v v = *(const float4v*)(g + 4 * j);
      u16* dst = xbuf + (j >> 5) * WHH_LP + (j & 31) * 4;
      dst[0] = f2bf(v[0] * CH1_); dst[1] = f2bf(v[1] * CH1_);
      dst[2] = f2bf(v[2] * CH1_); dst[3] = f2bf(v[3] * CH1_);
    }
  }
  __syncthreads();
#pragma unroll
  for (int blk = 0; blk < 2; blk++)
#pragma unroll
    for (int kk = 0; kk < 4; kk++)
      Af[blk][2 + kk] = *(const short8*)(xbuf + (blk * 128 + nl) * WHH_LP + kk * 32 + q * 8);
  __syncthreads();
  {  // Round 3: Whh rows 256..511 (block 2 -> CH2, block 3 -> CH1)
    const float* g = Whh + ((size_t)s * 512 + 256) * 128;
#pragma unroll
    for (int it = 0; it < 16; it++) {
      int j = tid + it * 512;
      float4v v = *(const float4v*)(g + 4 * j);
      const float sc = ((j >> 5) < 128) ? CH2_ : CH1_;
      u16* dst = xbuf + (j >> 5) * WHH_LP + (j & 31) * 4;
      dst[0] = f2bf(v[0] * sc); dst[1] = f2bf(v[1] * sc);
      dst[2] = f2bf(v[2] * sc); dst[3] = f2bf(v[3] * sc);
    }
  }
  __syncthreads();
#pragma unroll
  for (int blk = 2; blk < 4; blk++)
#pragma unroll
    for (int kk = 0; kk < 4; kk++)
      Af[blk][2 + kk] = *(const short8*)(xbuf + ((blk - 2) * 128 + nl) * WHH_LP + kk * 32 + q * 8);
  __syncthreads();

  // ---- E: precompute GNN features into xbuf (weights now in registers)
  {
    const int k = tid & 63;
    const int bb = (tid >> 6) & 3;
    const int th = tid >> 8;
    const float wrk = wr_s[k], wvk = wv_s[k], bgk = bg_s[k];
    for (int i = 0; i < T_ / 2; i++) {
      const int t = th * (T_ / 2) + i;
      const float xv = xh_lds[bb][t] * wrk + ag_lds[bb][t] * wvk + bgk;
      xbuf[t * (4 * XP_) + bb * XP_ + k] = f2bf(lrelu(xv));
    }
  }
  __syncthreads();

  // ---- recurrent loop. Per step: 48 MFMA/wave (16 x-part prefetched before
  // the barrier, 32 h-part after); one activation per lane; one barrier.
  floatx4 accNA[4], accNB[4];
  {
    short8 BxA0 = *(const short8*)(xbuf + b * XP_ + q * 8);
    short8 BxA1 = *(const short8*)(xbuf + b * XP_ + 32 + q * 8);
    short8 BxB0 = *(const short8*)(xbuf + (2 + b) * XP_ + q * 8);
    short8 BxB1 = *(const short8*)(xbuf + (2 + b) * XP_ + 32 + q * 8);
#pragma unroll
    for (int blk = 0; blk < 4; blk++) {
      accNA[blk] = __builtin_amdgcn_mfma_f32_16x16x32_bf16(Af[blk][0], BxA0, bias_init[blk], 0, 0, 0);
      accNA[blk] = __builtin_amdgcn_mfma_f32_16x16x32_bf16(Af[blk][1], BxA1, accNA[blk], 0, 0, 0);
      accNB[blk] = __builtin_amdgcn_mfma_f32_16x16x32_bf16(Af[blk][0], BxB0, bias_init[blk], 0, 0, 0);
      accNB[blk] = __builtin_amdgcn_mfma_f32_16x16x32_bf16(Af[blk][1], BxB1, accNB[blk], 0, 0, 0);
    }
  }
  float c = 0.f;
#pragma unroll 2
  for (int t = 0; t < T_; t++) {
    const int p = t & 1, pn = p ^ 1;
    // both streams' h-fragments (post-barrier)
    short8 BhA[4], BhB[4];
#pragma unroll
    for (int kk = 0; kk < 4; kk++) {
      BhA[kk] = *(const short8*)(hbuf + (p * 2 + b) * HP_ + kk * 32 + q * 8);
      BhB[kk] = *(const short8*)(hbuf + ((2 + p) * 2 + b) * HP_ + kk * 32 + q * 8);
    }
    // h-MFMAs; first one consumes accN as C (accN dies -> lower reg pressure)
    floatx4 aA[4], aB[4];
#pragma unroll
    for (int blk = 0; blk < 4; blk++) {
      aA[blk] = __builtin_amdgcn_mfma_f32_16x16x32_bf16(Af[blk][2], BhA[0], accNA[blk], 0, 0, 0);
      aB[blk] = __builtin_amdgcn_mfma_f32_16x16x32_bf16(Af[blk][2], BhB[0], accNB[blk], 0, 0, 0);
    }
#pragma unroll
    for (int kk = 1; kk < 4; kk++)
#pragma unroll
      for (int blk = 0; blk < 4; blk++) {
        aA[blk] = __builtin_amdgcn_mfma_f32_16x16x32_bf16(Af[blk][2 + kk], BhA[kk], aA[blk], 0, 0, 0);
        aB[blk] = __builtin_amdgcn_mfma_f32_16x16x32_bf16(Af[blk][2 + kk], BhB[kk], aB[blk], 0, 0, 0);
      }
    // prefetch next step's x-part (independent of this step's h)
    if (t + 1 < T_) {
      const u16* xr = xbuf + (t + 1) * (4 * XP_);
      short8 BxA0 = *(const short8*)(xr + b * XP_ + q * 8);
      short8 BxA1 = *(const short8*)(xr + b * XP_ + 32 + q * 8);
      short8 BxB0 = *(const short8*)(xr + (2 + b) * XP_ + q * 8);
      short8 BxB1 = *(const short8*)(xr + (2 + b) * XP_ + 32 + q * 8);
#pragma unroll
      for (int blk = 0; blk < 4; blk++) {
        accNA[blk] = __builtin_amdgcn_mfma_f32_16x16x32_bf16(Af[blk][0], BxA0, bias_init[blk], 0, 0, 0);
        accNA[blk] = __builtin_amdgcn_mfma_f32_16x16x32_bf16(Af[blk][1], BxA1, accNA[blk], 0, 0, 0);
        accNB[blk] = __builtin_amdgcn_mfma_f32_16x16x32_bf16(Af[blk][0], BxB0, bias_init[blk], 0, 0, 0);
        accNB[blk] = __builtin_amdgcn_mfma_f32_16x16x32_bf16(Af[blk][1], BxB1, accNB[blk], 0, 0, 0);
      }
    }
    // activation: each lane owns one (stream, batch, row) element
    {
      const float gi = str ? sel4(aB[0], rho) : sel4(aA[0], rho);
      const float gf = str ? sel4(aB[1], rho) : sel4(aA[1], rho);
      const float gg = str ? sel4(aB[2], rho) : sel4(aA[2], rho);
      const float go = str ? sel4(aB[3], rho) : sel4(aA[3], rho);
      c = sigm_pre(gf) * c + sigm_pre(gi) * tanh_pre(gg);
      const float hh = sigm_pre(go) * tanh_fast(c);
      hbuf[(str * 4 + pn * 2 + b) * HP_ + w * 16 + q * 4 + rho] = f2bf(hh);
    }
    __syncthreads();
  }

  // ---- head: final h at p=0 of each stream
  if (tid < 4 * FUT_) {
    const int bb = tid / FUT_;   // 0..3 -> (str = bb>>1, b = bb&1)
    const int f = tid % FUT_;
    float a = blin[f];
#pragma unroll 8
    for (int k = 0; k < HL_; k++)
      a += b2f(hbuf[((bb >> 1) * 4 + (bb & 1)) * HP_ + k]) * Wlin[f * HL_ + k];
    out[((size_t)(bg * 4 + bb) * NH_ + s) * FUT_ + f] = lrelu(a);
  }
}

extern "C" void kernel_launch(void* const* d_in, const int* in_sizes, int n_in,
                              void* d_out, int out_size, void* d_ws, size_t ws_size,
                              hipStream_t stream) {
  const float* dm = (const float*)d_in[0];
  const float* dh = (const float*)d_in[1];
  const int* eidx = (const int*)d_in[2];
  const float* Wroot = (const float*)d_in[3];
  const float* Wrel = (const float*)d_in[4];
  const float* bgnn = (const float*)d_in[5];
  const float* Wih = (const float*)d_in[6];
  const float* Whh = (const float*)d_in[7];
  const float* bih = (const float*)d_in[8];
  const float* bhh = (const float*)d_in[9];
  const float* Wlin = (const float*)d_in[10];
  const float* blin = (const float*)d_in[11];
  float* out = (float*)d_out;

  fused_kernel<<<256, 512, 0, stream>>>(dm, dh, eidx, Wroot, Wrel, bgnn, Wih, Whh,
                                        bih, bhh, Wlin, blin, out);
}

// Round 9
// 199.033 us; speedup vs baseline: 4.5487x; 1.3186x over previous
//
#include <hip/hip_runtime.h>

typedef unsigned short u16;
typedef unsigned int u32;
typedef __attribute__((ext_vector_type(8))) short short8;
typedef __attribute__((ext_vector_type(4))) float floatx4;
typedef __attribute__((ext_vector_type(4))) float float4v;
typedef __attribute__((ext_vector_type(2))) u32 uint2v;

#define B_ 32
#define T_ 168
#define NH_ 32
#define NM_ 64
#define E_ 384
#define HL_ 128
#define FUT_ 24
#define SLOPE_ 0.01f
#define HP_ 144    // hbuf stride per (p,b) row (u16)
#define TW_ 21     // chunk depth (168 = 8*21)
#define ZP_ 528    // zwin row stride per col=(i*4+b) (u16): b-stride 8 banks -> 16 distinct
#define XSP_ 72    // xstage row stride per col (u16)
#define WIH_LP 72  // Wih staging row stride (u16): 512*72 = 36864 <= 44352 (zwin)
#define WHH_LP 136 // Whh staging row stride (u16): 256*136 = 34816 <= 44352
#define CH1_ (-1.4426950408889634f)  // folded into i,f,o gate rows
#define CH2_ (2.8853900817779268f)   // folded into g gate rows

static __device__ __forceinline__ float b2f(u16 u) {
  u32 v = ((u32)u) << 16;
  return __builtin_bit_cast(float, v);
}
static __device__ __forceinline__ u16 f2bf(float f) {
  u32 x = __builtin_bit_cast(u32, f);
  u32 r = (x + 0x7fffu + ((x >> 16) & 1u)) >> 16;
  return (u16)r;
}
static __device__ __forceinline__ float fexp2(float x) { return __builtin_amdgcn_exp2f(x); }
static __device__ __forceinline__ float frcp(float x) { return __builtin_amdgcn_rcpf(x); }
// gates arrive PRE-SCALED by CH1_/CH2_ (folded into weights+bias at staging)
static __device__ __forceinline__ float sigm_pre(float x) { return frcp(1.0f + fexp2(x)); }
static __device__ __forceinline__ float tanh_pre(float x) { return 1.0f - 2.0f * frcp(1.0f + fexp2(x)); }
static __device__ __forceinline__ float tanh_fast(float x) {
  return 1.0f - 2.0f * frcp(1.0f + fexp2(2.8853900817779268f * x));
}
static __device__ __forceinline__ float sel4(floatx4 v, int r) {
  float m0 = (r & 1) ? v[1] : v[0];
  float m1 = (r & 1) ? v[3] : v[2];
  return (r & 2) ? m1 : m0;
}
static __device__ __forceinline__ float lrelu(float x) { return fmaxf(x, SLOPE_ * x); }

// Fused GNN + per-station LSTM + head.
// Grid: 256 WGs = 32 stations x 8 bgroups x 4 batches. 512 thr = 8 waves,
// 2 waves/SIMD (register-resident weights need ~96 VGPR -> max 2 waves/SIMD).
// Key change vs r5: the x-part GEMM (Z = scaled(Wih)·x + scaled(bias)) is done
// in bulk per 21-step chunk (48 MFMA/wave/chunk) into an LDS z-window; per step
// the C-init is a prefetched ds_read_b64 + cvt. Post-barrier path = 4 Bh reads
// -> 16 h-MFMAs -> activation -> write -> barrier.
__launch_bounds__(512, 2)
__global__ void fused_kernel(const float* __restrict__ dm, const float* __restrict__ dh,
                             const int* __restrict__ eidx,
                             const float* __restrict__ Wroot, const float* __restrict__ Wrel,
                             const float* __restrict__ bgnn,
                             const float* __restrict__ Wih, const float* __restrict__ Whh,
                             const float* __restrict__ bih, const float* __restrict__ bhh,
                             const float* __restrict__ Wlin, const float* __restrict__ blin,
                             float* __restrict__ out) {
  const int s = blockIdx.x & 31;
  const int bg = blockIdx.x >> 5;  // 0..7
  const int tid = threadIdx.x;
  const int w = tid >> 6;
  const int lane = tid & 63;
  const int cm = lane & 15;
  const int q = lane >> 4;
  const int b = cm & 3;    // real batch column (cols 4..15 duplicate 0..3)
  const int rho = cm >> 2; // acc element this lane activates

  // zwin doubles as the weight-staging overlay in the preamble
  __shared__ __align__(16) u16 zwin[TW_ * 4 * ZP_];   // 44352 u16 = 88.7 KB
  __shared__ __align__(16) u16 xstage[96 * XSP_];     // 13.8 KB
  __shared__ __align__(16) u16 hbuf[2 * 4 * HP_];     // [p][b][HP_]
  __shared__ float xh_lds[4][T_];
  __shared__ float ag_lds[4][T_];
  __shared__ float wr_s[64], wv_s[64], bg_s[64];
  __shared__ int srcs[E_];
  __shared__ int nsrc, iflag;

  // ---- A: init
  if (tid == 0) { nsrc = 0; iflag = 0; }
  for (int i = tid; i < 2 * 4 * HP_; i += 512) hbuf[i] = 0;
  __syncthreads();

  // ---- B: int64-vs-int32 edge_index probe
  {
    int odd = 0;
    for (int e = tid; e < E_; e += 512) odd |= eidx[2 * e + 1];
    if (odd) atomicOr(&iflag, 1);
  }
  __syncthreads();
  const bool i32 = iflag != 0;

  // ---- C: in-edges; small tensors; bias (gate-scale folded; used as bulk-GEMM C)
  for (int e = tid; e < E_; e += 512) {
    int se = i32 ? eidx[e] : eidx[2 * e];
    int de = i32 ? eidx[E_ + e] : eidx[2 * E_ + 2 * e];
    if (de == s) { int i = atomicAdd(&nsrc, 1); srcs[i] = se; }
  }
  if (tid < 64) { wr_s[tid] = Wroot[tid]; wv_s[tid] = Wrel[tid]; bg_s[tid] = bgnn[tid]; }
  for (int i = tid; i < 4 * T_; i += 512) {
    int bb = i / T_, t = i % T_;
    xh_lds[bb][t] = dh[((size_t)(bg * 4 + bb) * T_ + t) * NH_ + s];
  }
  floatx4 bias_init[4];
#pragma unroll
  for (int blk = 0; blk < 4; blk++) {
    const float sc = (blk == 2) ? CH2_ : CH1_;
#pragma unroll
    for (int r = 0; r < 4; r++) {
      const int nb = blk * 128 + w * 16 + q * 4 + r;
      bias_init[blk][r] = (bih[s * 512 + nb] + bhh[s * 512 + nb]) * sc;
    }
  }
  __syncthreads();

  // ---- D: per-(b,t) aggregation (avg ~4 in-edges/station)
  const int ns = nsrc;
  for (int i = tid; i < 4 * T_; i += 512) {
    int bb = i / T_, t = i % T_;
    size_t gb = (size_t)(bg * 4 + bb) * T_ + t;
    float a = 0.f;
    for (int j = 0; j < ns; j++) {
      int sr = srcs[j];
      a += (sr < NH_) ? dh[gb * NH_ + sr] : dm[gb * NM_ + (sr - NH_)];
    }
    ag_lds[bb][t] = a;
  }

  // ---- W: coalesced LDS-staged weight load (overlay = zwin), 3 unrolled rounds,
  // static Af indices (register residency), gate scales folded at convert.
  short8 Af[4][6];
  const int nl = w * 16 + cm;  // gate-row within a 128-block (A row m = cm)
  __syncthreads();
  {  // Round 1: all of Wih (512 rows x 64)
    const float* g = Wih + (size_t)s * 512 * 64;
#pragma unroll
    for (int it = 0; it < 16; it++) {
      int j = tid + it * 512;
      float4v v = *(const float4v*)(g + 4 * j);
      const float sc = (((j >> 4) >> 7) == 2) ? CH2_ : CH1_;
      u16* dst = zwin + (j >> 4) * WIH_LP + (j & 15) * 4;
      dst[0] = f2bf(v[0] * sc); dst[1] = f2bf(v[1] * sc);
      dst[2] = f2bf(v[2] * sc); dst[3] = f2bf(v[3] * sc);
    }
  }
  __syncthreads();
#pragma unroll
  for (int blk = 0; blk < 4; blk++)
#pragma unroll
    for (int kk = 0; kk < 2; kk++)
      Af[blk][kk] = *(const short8*)(zwin + (blk * 128 + nl) * WIH_LP + kk * 32 + q * 8);
  __syncthreads();
  {  // Round 2: Whh rows 0..255 (gate blocks 0,1 -> CH1)
    const float* g = Whh + (size_t)s * 512 * 128;
#pragma unroll
    for (int it = 0; it < 16; it++) {
      int j = tid + it * 512;
      float4v v = *(const float4v*)(g + 4 * j);
      u16* dst = zwin + (j >> 5) * WHH_LP + (j & 31) * 4;
      dst[0] = f2bf(v[0] * CH1_); dst[1] = f2bf(v[1] * CH1_);
      dst[2] = f2bf(v[2] * CH1_); dst[3] = f2bf(v[3] * CH1_);
    }
  }
  __syncthreads();
#pragma unroll
  for (int blk = 0; blk < 2; blk++)
#pragma unroll
    for (int kk = 0; kk < 4; kk++)
      Af[blk][2 + kk] = *(const short8*)(zwin + (blk * 128 + nl) * WHH_LP + kk * 32 + q * 8);
  __syncthreads();
  {  // Round 3: Whh rows 256..511 (block 2 -> CH2, block 3 -> CH1)
    const float* g = Whh + ((size_t)s * 512 + 256) * 128;
#pragma unroll
    for (int it = 0; it < 16; it++) {
      int j = tid + it * 512;
      float4v v = *(const float4v*)(g + 4 * j);
      const float sc = ((j >> 5) < 128) ? CH2_ : CH1_;
      u16* dst = zwin + (j >> 5) * WHH_LP + (j & 31) * 4;
      dst[0] = f2bf(v[0] * sc); dst[1] = f2bf(v[1] * sc);
      dst[2] = f2bf(v[2] * sc); dst[3] = f2bf(v[3] * sc);
    }
  }
  __syncthreads();
#pragma unroll
  for (int blk = 2; blk < 4; blk++)
#pragma unroll
    for (int kk = 0; kk < 4; kk++)
      Af[blk][2 + kk] = *(const short8*)(zwin + ((blk - 2) * 128 + nl) * WHH_LP + kk * 32 + q * 8);

  // ---- recurrent: 8 chunks x 21 steps
  float c = 0.f;
#pragma unroll 1
  for (int ch = 0; ch < 8; ch++) {
    const int tb = ch * TW_;
    __syncthreads();  // zwin/xstage free (prev chunk fully consumed)
    // build X (GNN features) for this chunk, B-frag-friendly layout [col][k]
    for (int idx = tid; idx < 84 * 64; idx += 512) {
      const int col = idx >> 6, k = idx & 63;
      const int i = col >> 2, bb = col & 3;
      const float xv = xh_lds[bb][tb + i] * wr_s[k] + ag_lds[bb][tb + i] * wv_s[k] + bg_s[k];
      xstage[col * XSP_ + k] = f2bf(lrelu(xv));
    }
    __syncthreads();
    // bulk GEMM: z[col][n] = scaled(Wih)·x + scaled(bias); 48 MFMA/wave
#pragma unroll
    for (int ct = 0; ct < 6; ct++) {
      const int col = ct * 16 + cm;
      short8 Bx0 = *(const short8*)(xstage + col * XSP_ + q * 8);
      short8 Bx1 = *(const short8*)(xstage + col * XSP_ + 32 + q * 8);
#pragma unroll
      for (int blk = 0; blk < 4; blk++) {
        floatx4 za = __builtin_amdgcn_mfma_f32_16x16x32_bf16(Af[blk][0], Bx0, bias_init[blk], 0, 0, 0);
        za = __builtin_amdgcn_mfma_f32_16x16x32_bf16(Af[blk][1], Bx1, za, 0, 0, 0);
        if (col < 84) {
          // C/D: lane holds rows q*4+0..3 of this 16-row tile, col = cm
          u16 pk[4];
#pragma unroll
          for (int r = 0; r < 4; r++) pk[r] = f2bf(za[r]);
          *(uint2v*)(zwin + col * ZP_ + blk * 128 + w * 16 + q * 4) = *(uint2v*)pk;
        }
      }
    }
    __syncthreads();

    // prefetch z for step 0 of this chunk
    uint2v z4[4];
#pragma unroll
    for (int blk = 0; blk < 4; blk++)
      z4[blk] = *(const uint2v*)(zwin + b * ZP_ + blk * 128 + w * 16 + q * 4);

#pragma unroll 3
    for (int i = 0; i < TW_; i++) {
      const int t = tb + i;
      const int p = t & 1, pn = p ^ 1;
      // post-barrier critical path: Bh loads -> 16 MFMAs -> activation
      short8 Bh[4];
#pragma unroll
      for (int kk = 0; kk < 4; kk++)
        Bh[kk] = *(const short8*)(hbuf + (p * 4 + b) * HP_ + kk * 32 + q * 8);

      floatx4 acc[4];
#pragma unroll
      for (int blk = 0; blk < 4; blk++) {
        const u32 w0 = z4[blk][0], w1 = z4[blk][1];
        acc[blk][0] = __builtin_bit_cast(float, w0 << 16);
        acc[blk][1] = __builtin_bit_cast(float, w0 & 0xFFFF0000u);
        acc[blk][2] = __builtin_bit_cast(float, w1 << 16);
        acc[blk][3] = __builtin_bit_cast(float, w1 & 0xFFFF0000u);
      }
#pragma unroll
      for (int kk = 0; kk < 4; kk++)
#pragma unroll
        for (int blk = 0; blk < 4; blk++)
          acc[blk] = __builtin_amdgcn_mfma_f32_16x16x32_bf16(Af[blk][2 + kk], Bh[kk], acc[blk], 0, 0, 0);

      // activation: one element per lane (row = w*16+q*4+rho, batch b)
      const float gi = sel4(acc[0], rho);
      const float gf = sel4(acc[1], rho);
      const float gg = sel4(acc[2], rho);
      const float go = sel4(acc[3], rho);
      c = sigm_pre(gf) * c + sigm_pre(gi) * tanh_pre(gg);
      const float hh = sigm_pre(go) * tanh_fast(c);
      hbuf[(pn * 4 + b) * HP_ + w * 16 + q * 4 + rho] = f2bf(hh);

      // prefetch next step's z (chunk-static; no barrier dependence)
      if (i + 1 < TW_) {
#pragma unroll
        for (int blk = 0; blk < 4; blk++)
          z4[blk] = *(const uint2v*)(zwin + ((i + 1) * 4 + b) * ZP_ + blk * 128 + w * 16 + q * 4);
      }
      __syncthreads();
    }
  }

  // ---- head: final h in hbuf p=0 (t=167 wrote pn=0)
  if (tid < 4 * FUT_) {
    const int bb = tid / FUT_;
    const int f = tid % FUT_;
    float a = blin[f];
#pragma unroll 8
    for (int k = 0; k < HL_; k++) a += b2f(hbuf[bb * HP_ + k]) * Wlin[f * HL_ + k];
    out[((size_t)(bg * 4 + bb) * NH_ + s) * FUT_ + f] = lrelu(a);
  }
}

extern "C" void kernel_launch(void* const* d_in, const int* in_sizes, int n_in,
                              void* d_out, int out_size, void* d_ws, size_t ws_size,
                              hipStream_t stream) {
  const float* dm = (const float*)d_in[0];
  const float* dh = (const float*)d_in[1];
  const int* eidx = (const int*)d_in[2];
  const float* Wroot = (const float*)d_in[3];
  const float* Wrel = (const float*)d_in[4];
  const float* bgnn = (const float*)d_in[5];
  const float* Wih = (const float*)d_in[6];
  const float* Whh = (const float*)d_in[7];
  const float* bih = (const float*)d_in[8];
  const float* bhh = (const float*)d_in[9];
  const float* Wlin = (const float*)d_in[10];
  const float* blin = (const float*)d_in[11];
  float* out = (float*)d_out;

  fused_kernel<<<256, 512, 0, stream>>>(dm, dh, eidx, Wroot, Wrel, bgnn, Wih, Whh,
                                        bih, bhh, Wlin, blin, out);
}